// Round 7
// baseline (203.511 us; speedup 1.0000x reference)
//
#include <hip/hip_runtime.h>
#include <hip/hip_bf16.h>

// MFVIConstituency: B=16, S=128, MAX_ITER=3.
// q_new[b,i,j] = s_span[b,i,j] + sum_k sigmoid(q[b,i,k]) * sp[b,i,j,k]
// sp[b,i,j,k]  = s_pair[b,i,j,k] * ( mask[b,i,j] & (k!=min(i,j)) & (k!=max(i,j))
//                                     & (mask[b,j,k]|mask[b,k,j]) )
//
// Round-7: no compaction. Direct row ownership (j = row0+8s) with exec-masked
// loads skipping dead rows; unconditional butterfly commit (dead rows reduce
// to q=s_span = correct output). k!=j clear folded into pack (diagonal),
// k!=i clear folded into init (block-uniform). 3 barriers, dbuf prow.

#define S 128
#define MB_STRIDE 132     // mask byte tile: transposed byte reads conflict-free

static __device__ __forceinline__ float fsig(float x) {
    return __builtin_amdgcn_rcpf(1.0f + __expf(-x));
}

// -------- pre-pack per batch: span bitmasks (diagonal pre-cleared) --------
__global__ __launch_bounds__(256, 2) void pack_masks(
    const int* __restrict__ mask,
    unsigned* __restrict__ spanw)        // [B*S*4] bit k of row j: (m[j,k]|m[k,j]) & (k!=j)
{
    __shared__ unsigned char mb[S * MB_STRIDE];   // 16896 B
    const int t = threadIdx.x, b = blockIdx.x;
    const int* mrow = mask + (long long)b * (S * S);
    #pragma unroll
    for (int s2 = 0; s2 < 16; ++s2) {
        int f4 = t + 256 * s2;            // int4 index 0..4095
        int j  = f4 >> 5;
        int k0 = (f4 & 31) * 4;
        int4 v = *(const int4*)(mrow + f4 * 4);
        unsigned packed = (v.x ? 1u : 0u)
                        | ((v.y ? 1u : 0u) << 8)
                        | ((v.z ? 1u : 0u) << 16)
                        | ((v.w ? 1u : 0u) << 24);
        *(unsigned*)(mb + j * MB_STRIDE + k0) = packed;
    }
    __syncthreads();

    #pragma unroll
    for (int r = 0; r < 2; ++r) {
        int task = t * 2 + r;             // (j, w)
        int j = task >> 2, w = task & 3;
        unsigned sbits = 0;
        #pragma unroll
        for (int c = 0; c < 32; ++c) {
            int k = w * 32 + c;
            sbits |= ((mb[j * MB_STRIDE + k] | mb[k * MB_STRIDE + j]) ? 1u : 0u) << c;
        }
        if ((j >> 5) == w) sbits &= ~(1u << (j & 31));   // k != j (diagonal)
        spanw[(b * S + j) * 4 + w] = sbits;
    }
}

// -------- main: one block per (b,i); 3 barriers; butterfly reduce --------
__global__ __launch_bounds__(256, 4) void mfvi_main(
    const float* __restrict__ s_span,
    const float* __restrict__ s_pair,
    const int* __restrict__ mask,
    const unsigned* __restrict__ spanw,
    float* __restrict__ out)
{
    __shared__ unsigned sw_l[S * 4];   // 2048 B (bit i already cleared)
    __shared__ float    prow2[2][S];   // double-buffered sigmoid(q)
    __shared__ float    qsv [S];
    __shared__ int      mrow_l[S];     // mask[b,i,*] row

    const int t  = threadIdx.x;
    const int bi = blockIdx.x;        // b*128 + i
    const int i  = bi & (S - 1);
    const int b  = bi >> 7;
    const int row0 = t >> 5;          // 0..7  (half-wave id)
    const int L    = t & 31;          // lane within half-wave
    const int c4   = L * 4;           // k base 0..124
    const float* tile = s_pair + (long long)bi * (S * S);
    float* outrow = out + (long long)bi * S;

    // ---- init (single barrier) ----
    if (t < S) {
        uint4 sw = *(const uint4*)&spanw[(b * S + t) * 4];
        ((unsigned*)&sw)[i >> 5] &= ~(1u << (i & 31));   // k != i, block-uniform
        *(uint4*)&sw_l[t * 4] = sw;
        mrow_l[t] = mask[(long long)bi * S + t];
        float sv = s_span[(long long)bi * S + t];
        qsv[t] = sv;
        float p0 = fsig(sv);
        prow2[0][t] = p0;
        prow2[1][t] = p0;             // dead rows keep p0 in both buffers
    }
    __syncthreads();

    // row predicate bits for this thread's 16 rows (broadcast LDS reads)
    unsigned rowbits = 0;
    #pragma unroll
    for (int s = 0; s < 16; ++s)
        rowbits |= (mrow_l[row0 + 8 * s] ? 1u : 0u) << s;

    // ---- load active rows; apply span mask (lo/hi already folded) ----
    float4 v[16];
    #pragma unroll
    for (int s = 0; s < 16; ++s) {
        v[s] = make_float4(0.f, 0.f, 0.f, 0.f);
        if (rowbits & (1u << s)) {
            int j = row0 + 8 * s;
            float4 x = *(const float4*)(tile + j * S + c4);
            unsigned cs = sw_l[j * 4 + (L >> 3)] >> (c4 & 31);
            x.x = __int_as_float(__float_as_int(x.x) & (((int)(cs << 31)) >> 31));
            x.y = __int_as_float(__float_as_int(x.y) & (((int)(cs << 30)) >> 31));
            x.z = __int_as_float(__float_as_int(x.z) & (((int)(cs << 29)) >> 31));
            x.w = __int_as_float(__float_as_int(x.w) & (((int)(cs << 28)) >> 31));
            v[s] = x;
        }
    }

    // ---- 3 MFVI iterations; merging butterfly: lane L ends with row L&15 ----
    #pragma unroll
    for (int it = 0; it < 3; ++it) {
        const float* pr = prow2[it & 1];
        float*       pw = prow2[(it + 1) & 1];
        float4 p = *(const float4*)&pr[c4];     // 2-way broadcast read (free)
        float acc[16];
        #pragma unroll
        for (int s = 0; s < 16; ++s)            // dead rows: v[s]==0 -> acc 0
            acc[s] = v[s].x * p.x + v[s].y * p.y + v[s].z * p.z + v[s].w * p.w;

        // 16 -> 8 -> 4 -> 2 -> 1 values, lane bit n selects s bit n
        #pragma unroll
        for (int m = 0; m < 8; ++m) {
            float a = acc[2 * m], bb = acc[2 * m + 1];
            float sent = (L & 1) ? a : bb;
            float keep = (L & 1) ? bb : a;
            acc[m] = keep + __shfl_xor(sent, 1);
        }
        #pragma unroll
        for (int m = 0; m < 4; ++m) {
            float a = acc[2 * m], bb = acc[2 * m + 1];
            float sent = (L & 2) ? a : bb;
            float keep = (L & 2) ? bb : a;
            acc[m] = keep + __shfl_xor(sent, 2);
        }
        #pragma unroll
        for (int m = 0; m < 2; ++m) {
            float a = acc[2 * m], bb = acc[2 * m + 1];
            float sent = (L & 4) ? a : bb;
            float keep = (L & 4) ? bb : a;
            acc[m] = keep + __shfl_xor(sent, 4);
        }
        float r;
        {
            float a = acc[0], bb = acc[1];
            float sent = (L & 8) ? a : bb;
            float keep = (L & 8) ? bb : a;
            r = keep + __shfl_xor(sent, 8);
        }
        r += __shfl_xor(r, 16);                 // full 32-lane row sum

        if (L < 16) {                            // 16 parallel commits, ALL rows
            int j = row0 + 8 * L;
            float q = qsv[j] + r;                // dead row: r==0 -> q=s_span (correct)
            if (it < 2) pw[j] = fsig(q);
            else        outrow[j] = fsig(q);
        }
        if (it < 2) __syncthreads();
    }
}

extern "C" void kernel_launch(void* const* d_in, const int* in_sizes, int n_in,
                              void* d_out, int out_size, void* d_ws, size_t ws_size,
                              hipStream_t stream) {
    const float* s_span = (const float*)d_in[0];
    const float* s_pair = (const float*)d_in[1];
    const int*   mask   = (const int*)d_in[2];
    float*       out    = (float*)d_out;

    int num_rows = in_sizes[0] / S;        // B*S = 2048
    int B        = in_sizes[2] / (S * S);  // 16

    unsigned* ws_span = (unsigned*)d_ws;   // B*S*4 uints = 32 KB

    pack_masks<<<B, 256, 0, stream>>>(mask, ws_span);
    mfvi_main<<<num_rows, 256, 0, stream>>>(s_span, s_pair, mask, ws_span, out);
}

// Round 8
// 202.625 us; speedup vs baseline: 1.0044x; 1.0044x over previous
//
#include <hip/hip_runtime.h>
#include <hip/hip_bf16.h>

// MFVIConstituency: B=16, S=128, MAX_ITER=3.
// q_new[b,i,j] = s_span[b,i,j] + sum_k sigmoid(q[b,i,k]) * sp[b,i,j,k]
// sp[b,i,j,k]  = s_pair[b,i,j,k] * ( mask[b,i,j] & (k!=min(i,j)) & (k!=max(i,j))
//                                     & (mask[b,j,k]|mask[b,k,j]) )
//
// Round-8: prologue overlap. Row predicates come from a packed, block-uniform
// miw word (scalar load, no LDS/barrier), so the 16 predicated 64KB-tile
// loads issue at kernel start, overlapping the init loads + barrier instead
// of waiting behind them. Butterfly reduce, dbuf prow, 3 barriers retained.

#define S 128
#define MB_STRIDE 132     // mask byte tile: transposed byte reads conflict-free

static __device__ __forceinline__ float fsig(float x) {
    return __builtin_amdgcn_rcpf(1.0f + __expf(-x));
}

// -------- pre-pack per batch: span bits (diag-cleared) + packed row bits --------
__global__ __launch_bounds__(256, 2) void pack_masks(
    const int* __restrict__ mask,
    unsigned* __restrict__ spanw,   // [B*S*4] bit k of row j: (m[j,k]|m[k,j]) & (k!=j)
    unsigned* __restrict__ miw)     // [B*S*4] bit k of row j: m[j,k]
{
    __shared__ unsigned char mb[S * MB_STRIDE];   // 16896 B
    const int t = threadIdx.x, b = blockIdx.x;
    const int* mrow = mask + (long long)b * (S * S);
    #pragma unroll
    for (int s2 = 0; s2 < 16; ++s2) {
        int f4 = t + 256 * s2;            // int4 index 0..4095
        int j  = f4 >> 5;
        int k0 = (f4 & 31) * 4;
        int4 v = *(const int4*)(mrow + f4 * 4);
        unsigned packed = (v.x ? 1u : 0u)
                        | ((v.y ? 1u : 0u) << 8)
                        | ((v.z ? 1u : 0u) << 16)
                        | ((v.w ? 1u : 0u) << 24);
        *(unsigned*)(mb + j * MB_STRIDE + k0) = packed;
    }
    __syncthreads();

    #pragma unroll
    for (int r = 0; r < 2; ++r) {
        int task = t * 2 + r;             // (j, w)
        int j = task >> 2, w = task & 3;
        unsigned sbits = 0, mbits = 0;
        #pragma unroll
        for (int c = 0; c < 32; ++c) {
            int k = w * 32 + c;
            unsigned mjk = mb[j * MB_STRIDE + k];
            unsigned mkj = mb[k * MB_STRIDE + j];
            sbits |= ((mjk | mkj) ? 1u : 0u) << c;
            mbits |= (mjk ? 1u : 0u) << c;
        }
        if ((j >> 5) == w) sbits &= ~(1u << (j & 31));   // k != j (diagonal)
        spanw[(b * S + j) * 4 + w] = sbits;
        miw  [(b * S + j) * 4 + w] = mbits;
    }
}

// -------- main: one block per (b,i); loads hoisted above barrier --------
__global__ __launch_bounds__(256, 4) void mfvi_main(
    const float* __restrict__ s_span,
    const float* __restrict__ s_pair,
    const unsigned* __restrict__ spanw,
    const unsigned* __restrict__ miw,
    float* __restrict__ out)
{
    __shared__ unsigned sw_l[S * 4];   // 2048 B (bit i already cleared)
    __shared__ float    prow2[2][S];   // double-buffered sigmoid(q)
    __shared__ float    qsv [S];

    const int t  = threadIdx.x;
    const int bi = blockIdx.x;        // b*128 + i
    const int i  = bi & (S - 1);
    const int b  = bi >> 7;
    const int row0 = t >> 5;          // 0..7  (half-wave id)
    const int L    = t & 31;          // lane within half-wave
    const int c4   = L * 4;           // k base 0..124
    const float* tile = s_pair + (long long)bi * (S * S);
    float* outrow = out + (long long)bi * S;

    // ---- issue init loads (latency overlapped with the tile loads below) ----
    uint4 swv = make_uint4(0, 0, 0, 0);
    float sv = 0.f;
    if (t < S) {
        swv = *(const uint4*)&spanw[(b * S + t) * 4];
        sv  = s_span[(long long)bi * S + t];
    }

    // ---- row predicates from block-uniform packed mask row (scalar load) ----
    const unsigned mi0 = miw[bi * 4 + 0], mi1 = miw[bi * 4 + 1];
    const unsigned mi2 = miw[bi * 4 + 2], mi3 = miw[bi * 4 + 3];
    unsigned rowbits = 0;
    #pragma unroll
    for (int s = 0; s < 16; ++s) {
        unsigned w = (s < 4) ? mi0 : (s < 8) ? mi1 : (s < 12) ? mi2 : mi3;
        rowbits |= ((w >> (row0 + 8 * (s & 3))) & 1u) << s;   // bit of row row0+8s
    }

    // ---- 16 predicated tile loads: issue NOW, before any barrier ----
    float4 v[16];
    #pragma unroll
    for (int s = 0; s < 16; ++s) {
        v[s] = make_float4(0.f, 0.f, 0.f, 0.f);
        if (rowbits & (1u << s))
            v[s] = *(const float4*)(tile + (row0 + 8 * s) * S + c4);
    }

    // ---- init LDS while tile loads are in flight ----
    if (t < S) {
        ((unsigned*)&swv)[i >> 5] &= ~(1u << (i & 31));   // k != i, block-uniform
        *(uint4*)&sw_l[t * 4] = swv;
        qsv[t] = sv;
        float p0 = fsig(sv);
        prow2[0][t] = p0;
        prow2[1][t] = p0;             // dead rows keep p0 in both buffers
    }
    __syncthreads();

    // ---- apply span mask (k!=i, k!=j already folded into sw_l) ----
    #pragma unroll
    for (int s = 0; s < 16; ++s) {
        if (rowbits & (1u << s)) {
            int j = row0 + 8 * s;
            unsigned cs = sw_l[j * 4 + (L >> 3)] >> (c4 & 31);
            v[s].x = __int_as_float(__float_as_int(v[s].x) & (((int)(cs << 31)) >> 31));
            v[s].y = __int_as_float(__float_as_int(v[s].y) & (((int)(cs << 30)) >> 31));
            v[s].z = __int_as_float(__float_as_int(v[s].z) & (((int)(cs << 29)) >> 31));
            v[s].w = __int_as_float(__float_as_int(v[s].w) & (((int)(cs << 28)) >> 31));
        }
    }

    // ---- 3 MFVI iterations; merging butterfly: lane L ends with row L&15 ----
    #pragma unroll
    for (int it = 0; it < 3; ++it) {
        const float* pr = prow2[it & 1];
        float*       pw = prow2[(it + 1) & 1];
        float4 p = *(const float4*)&pr[c4];     // 2-way broadcast read (free)
        float acc[16];
        #pragma unroll
        for (int s = 0; s < 16; ++s)            // dead rows: v[s]==0 -> acc 0
            acc[s] = v[s].x * p.x + v[s].y * p.y + v[s].z * p.z + v[s].w * p.w;

        // 16 -> 8 -> 4 -> 2 -> 1 values, lane bit n selects s bit n
        #pragma unroll
        for (int m = 0; m < 8; ++m) {
            float a = acc[2 * m], bb = acc[2 * m + 1];
            float sent = (L & 1) ? a : bb;
            float keep = (L & 1) ? bb : a;
            acc[m] = keep + __shfl_xor(sent, 1);
        }
        #pragma unroll
        for (int m = 0; m < 4; ++m) {
            float a = acc[2 * m], bb = acc[2 * m + 1];
            float sent = (L & 2) ? a : bb;
            float keep = (L & 2) ? bb : a;
            acc[m] = keep + __shfl_xor(sent, 2);
        }
        #pragma unroll
        for (int m = 0; m < 2; ++m) {
            float a = acc[2 * m], bb = acc[2 * m + 1];
            float sent = (L & 4) ? a : bb;
            float keep = (L & 4) ? bb : a;
            acc[m] = keep + __shfl_xor(sent, 4);
        }
        float r;
        {
            float a = acc[0], bb = acc[1];
            float sent = (L & 8) ? a : bb;
            float keep = (L & 8) ? bb : a;
            r = keep + __shfl_xor(sent, 8);
        }
        r += __shfl_xor(r, 16);                 // full 32-lane row sum

        if (L < 16) {                            // 16 parallel commits, ALL rows
            int j = row0 + 8 * L;
            float q = qsv[j] + r;                // dead row: r==0 -> q=s_span (correct)
            if (it < 2) pw[j] = fsig(q);
            else        outrow[j] = fsig(q);
        }
        if (it < 2) __syncthreads();
    }
}

extern "C" void kernel_launch(void* const* d_in, const int* in_sizes, int n_in,
                              void* d_out, int out_size, void* d_ws, size_t ws_size,
                              hipStream_t stream) {
    const float* s_span = (const float*)d_in[0];
    const float* s_pair = (const float*)d_in[1];
    const int*   mask   = (const int*)d_in[2];
    float*       out    = (float*)d_out;

    int num_rows = in_sizes[0] / S;        // B*S = 2048
    int B        = in_sizes[2] / (S * S);  // 16

    unsigned* ws_span = (unsigned*)d_ws;                 // 32 KB
    unsigned* ws_miw  = ws_span + (size_t)B * S * 4;     // +32 KB

    pack_masks<<<B, 256, 0, stream>>>(mask, ws_span, ws_miw);
    mfvi_main<<<num_rows, 256, 0, stream>>>(s_span, s_pair, ws_span, ws_miw, out);
}